// Round 7
// baseline (402.200 us; speedup 1.0000x reference)
//
#include <hip/hip_runtime.h>

#define S_LEN 4096
#define DIM   256
#define QBLK  128
#define KVBLK 64
#define PERB  144            // chunk slots per batch (QBLK=128, CH=8 kv-tiles)
#define TILE_SH (KVBLK * DIM)   // shorts per 32KB tile image

typedef __attribute__((ext_vector_type(4))) float f32x4;
typedef __attribute__((ext_vector_type(8))) short bf16x8;
typedef __attribute__((ext_vector_type(4))) unsigned short u16x4;
typedef __attribute__((ext_vector_type(8))) unsigned short u16x8;

__device__ __forceinline__ unsigned short f2bf(float x) {
    union { float f; unsigned u; } v; v.f = x;
    unsigned r = v.u + 0x7FFFu + ((v.u >> 16) & 1u);
    return (unsigned short)(r >> 16);
}
__device__ __forceinline__ float bf2f(unsigned short h) {
    union { unsigned u; float f; } v; v.u = ((unsigned)h) << 16;
    return v.f;
}

// async global->LDS, 16B/lane; LDS dest = wave-uniform base + lane*16
__device__ __forceinline__ void g2l16(const unsigned short* g, unsigned short* s) {
    __builtin_amdgcn_global_load_lds(
        (const __attribute__((address_space(1))) unsigned int*)g,
        (__attribute__((address_space(3))) unsigned int*)s, 16, 0, 0);
}

// ---------- prepass: one block per (b,tile); coalesced image writes ----------
__global__ __launch_bounds__(256) void prepass(
        const float* __restrict__ K, const float* __restrict__ V,
        unsigned short* __restrict__ KW, unsigned short* __restrict__ VW) {
    __shared__ unsigned short vt[TILE_SH];
    const int tile = blockIdx.x;              // b*64 + t  (256 blocks)
    const int tid  = threadIdx.x;
    const float* ks = K + (size_t)tile * (KVBLK * DIM);
    const float* vs = V + (size_t)tile * (KVBLK * DIM);

    // K image: direct coalesced u16x8 writes (XOR swizzle permutes within rows)
    char* kw = (char*)(KW + (size_t)tile * TILE_SH);
#pragma unroll
    for (int j = 0; j < 8; ++j) {
        int u = j * 256 + tid;                // 16B-unit index
        int row = u >> 5, c8 = u & 31;
        f32x4 a  = *(const f32x4*)(ks + row * DIM + c8 * 8);
        f32x4 bb = *(const f32x4*)(ks + row * DIM + c8 * 8 + 4);
        u16x8 h;
        h[0] = f2bf(a[0]);  h[1] = f2bf(a[1]);  h[2] = f2bf(a[2]);  h[3] = f2bf(a[3]);
        h[4] = f2bf(bb[0]); h[5] = f2bf(bb[1]); h[6] = f2bf(bb[2]); h[7] = f2bf(bb[3]);
        unsigned off = (unsigned)(row * 512 + c8 * 16) ^ (unsigned)((row & 7) << 4);
        *(u16x8*)(kw + off) = h;
    }

    // V^T image: build in LDS (coalesced col reads), dump linearly
    {
        int col = tid;
#pragma unroll
        for (int r8 = 0; r8 < 8; ++r8) {
            u16x8 h;
#pragma unroll
            for (int e = 0; e < 8; ++e) h[e] = f2bf(vs[(r8 * 8 + e) * DIM + col]);
            unsigned off = (unsigned)(col * 128 + r8 * 16) ^ (unsigned)((col & 7) << 4);
            *(u16x8*)((char*)vt + off) = h;
        }
    }
    __syncthreads();
    char* vw = (char*)(VW + (size_t)tile * TILE_SH);
#pragma unroll
    for (int j = 0; j < 8; ++j) {
        int u = j * 256 + tid;
        *(u16x8*)(vw + u * 16) = *(const u16x8*)((const char*)vt + u * 16);
    }
}

// ---------- main flash kernel: 8 waves, QBLK=128 ----------
template<bool DIRECT>
__global__ __launch_bounds__(512, 4) void attn_part(
        const float* __restrict__ Qg, const unsigned short* __restrict__ KW,
        const unsigned short* __restrict__ VW, unsigned short* __restrict__ OP,
        float* __restrict__ ML, float* __restrict__ Og) {
    __shared__ unsigned short Ksh[TILE_SH];       // [64][256] bf16, swz image
    __shared__ unsigned short VshT[TILE_SH];      // [256][64] bf16 (V^T), swz image
    __shared__ unsigned short Psh[8][16 * KVBLK]; // per-wave [q=16][k=64] bf16, swz

    const int tid = threadIdx.x;
    const int w   = tid >> 6;      // wave 0..7
    const int l   = tid & 63;
    const int l15 = l & 15;
    const int lg  = l >> 4;

    int b, qt, t0, t1, pslot;
    if (DIRECT) {
        b = blockIdx.x & 3; qt = blockIdx.x >> 2;
        t0 = 0; t1 = 2 * qt + 2; pslot = 0;
    } else {
        const int id = blockIdx.x;
        b = id / PERB;
        int s = (PERB - 1) - (id - b * PERB);   // heavy chunks first
        int g = 0;
        while (s >= 4 * (g + 1)) { s -= 4 * (g + 1); ++g; }
        qt = 4 * g + s / (g + 1);
        const int chunk = s - (s / (g + 1)) * (g + 1);
        t0 = chunk * 8;
        t1 = min(t0 + 8, 2 * qt + 2);
        pslot = b * PERB + 2 * g * (g + 1) + (qt - 4 * g) * (g + 1) + chunk;
    }
    const int qbase = qt * QBLK;
    const int wqlo  = qbase + w * 16;   // this wave's lowest q-row

    // ---------- Q fragments (16 rows/wave, scale 1/16 folded) ----------
    const int qrow = wqlo + l15;
    const float* qp = Qg + (size_t)(b * S_LEN + qrow) * DIM + lg * 8;
    bf16x8 qf[8];
#pragma unroll
    for (int ks = 0; ks < 8; ++ks) {
        f32x4 a = *(const f32x4*)(qp + ks * 32);
        f32x4 c = *(const f32x4*)(qp + ks * 32 + 4);
        bf16x8 f;
        f[0] = (short)f2bf(a[0] * 0.0625f); f[1] = (short)f2bf(a[1] * 0.0625f);
        f[2] = (short)f2bf(a[2] * 0.0625f); f[3] = (short)f2bf(a[3] * 0.0625f);
        f[4] = (short)f2bf(c[0] * 0.0625f); f[5] = (short)f2bf(c[1] * 0.0625f);
        f[6] = (short)f2bf(c[2] * 0.0625f); f[7] = (short)f2bf(c[3] * 0.0625f);
        qf[ks] = f;
    }

    f32x4 acc[16];
#pragma unroll
    for (int i = 0; i < 16; ++i) acc[i] = (f32x4)0.0f;
    float mrun = -1e30f, lrun = 0.f;

    for (int t = t0; t < t1; ++t) {
        // ------- stage tile images via async global->LDS (8 instrs/wave) -------
        {
            const unsigned short* kimg = KW + (size_t)(b * 64 + t) * TILE_SH + w * 2048 + l * 8;
            const unsigned short* vimg = VW + (size_t)(b * 64 + t) * TILE_SH + w * 2048 + l * 8;
            unsigned short* kd = &Ksh[w * 2048];
            unsigned short* vd = &VshT[w * 2048];
#pragma unroll
            for (int i = 0; i < 4; ++i) {
                g2l16(kimg + i * 512, kd + i * 512);
                g2l16(vimg + i * 512, vd + i * 512);
            }
        }
        __syncthreads();

        const bool skip = (t * KVBLK >= wqlo + 16);          // tile fully masked for wave
        const bool msk  = (t * KVBLK + KVBLK - 1 >= wqlo);   // diagonal region

        if (!skip) {
            // ---------------- S^T = K (Q*scale)^T ----------------
            f32x4 sacc[4];
#pragma unroll
            for (int j = 0; j < 4; ++j) sacc[j] = (f32x4)0.0f;
#pragma unroll
            for (int ks = 0; ks < 8; ++ks) {
#pragma unroll
                for (int jt = 0; jt < 4; ++jt) {
                    int j = jt * 16 + l15;
                    unsigned off = (unsigned)(j * 512 + (ks * 32 + lg * 8) * 2);
                    off ^= (unsigned)((j & 7) << 4);
                    bf16x8 kb = *(const bf16x8*)((const char*)Ksh + off);
                    sacc[jt] = __builtin_amdgcn_mfma_f32_16x16x32_bf16(kb, qf[ks], sacc[jt], 0, 0, 0);
                }
            }

            // ---------------- causal mask (strict j < i) ----------------
            if (msk) {
                const int qg = wqlo + l15;
#pragma unroll
                for (int jt = 0; jt < 4; ++jt)
#pragma unroll
                    for (int rr = 0; rr < 4; ++rr) {
                        int kg = t * KVBLK + jt * 16 + lg * 4 + rr;
                        if (kg >= qg) sacc[jt][rr] = -3e38f;
                    }
            }

            // ---------------- online softmax, in registers ----------------
            {
                float m0 = fmaxf(fmaxf(sacc[0][0], sacc[0][1]), fmaxf(sacc[0][2], sacc[0][3]));
                float m1 = fmaxf(fmaxf(sacc[1][0], sacc[1][1]), fmaxf(sacc[1][2], sacc[1][3]));
                float m2 = fmaxf(fmaxf(sacc[2][0], sacc[2][1]), fmaxf(sacc[2][2], sacc[2][3]));
                float m3 = fmaxf(fmaxf(sacc[3][0], sacc[3][1]), fmaxf(sacc[3][2], sacc[3][3]));
                float mx = fmaxf(fmaxf(m0, m1), fmaxf(m2, m3));
                mx = fmaxf(mx, __shfl_xor(mx, 16));
                mx = fmaxf(mx, __shfl_xor(mx, 32));
                float mnew = fmaxf(mrun, mx);
                float corr = __expf(mrun - mnew);
                mrun = mnew;
                float ls = 0.f;
#pragma unroll
                for (int jt = 0; jt < 4; ++jt)
#pragma unroll
                    for (int rr = 0; rr < 4; ++rr) {
                        float p = __expf(sacc[jt][rr] - mnew);
                        sacc[jt][rr] = p;
                        ls += p;
                    }
                ls += __shfl_xor(ls, 16);
                ls += __shfl_xor(ls, 32);
                lrun = lrun * corr + ls;
#pragma unroll
                for (int nt = 0; nt < 16; ++nt) acc[nt] *= corr;
            }

            // ---------------- P^T -> per-wave LDS (4x ds_write_b64) ----------------
            {
                char* pw = (char*)&Psh[w][0];
                unsigned base = (unsigned)(l15 * 128 + lg * 8) ^ (unsigned)((l15 & 7) << 4);
#pragma unroll
                for (int jt = 0; jt < 4; ++jt) {
                    u16x4 pk;
                    pk.x = f2bf(sacc[jt][0]); pk.y = f2bf(sacc[jt][1]);
                    pk.z = f2bf(sacc[jt][2]); pk.w = f2bf(sacc[jt][3]);
                    *(u16x4*)(pw + (base ^ (unsigned)(jt * 32))) = pk;
                }
            }

            // ---------------- O^T += V^T P^T ----------------
#pragma unroll
            for (int ks = 0; ks < 2; ++ks) {
                unsigned poff = (unsigned)(l15 * 128 + ks * 64 + lg * 16);
                poff ^= (unsigned)((l15 & 7) << 4);
                bf16x8 pb = *(const bf16x8*)((const char*)&Psh[w][0] + poff);
#pragma unroll
                for (int nt = 0; nt < 16; ++nt) {
                    unsigned voff = (unsigned)((nt * 16 + l15) * 128 + ks * 64 + lg * 16);
                    voff ^= (unsigned)((l15 & 7) << 4);
                    bf16x8 va = *(const bf16x8*)((const char*)VshT + voff);
                    acc[nt] = __builtin_amdgcn_mfma_f32_16x16x32_bf16(va, pb, acc[nt], 0, 0, 0);
                }
            }
        }
        __syncthreads();
    }

    if (DIRECT) {
        float rl = (lrun > 0.f) ? (1.0f / lrun) : 0.f;
        float* ob = Og + (size_t)(b * S_LEN + wqlo + l15) * DIM;
#pragma unroll
        for (int nt = 0; nt < 16; ++nt) {
            f32x4 o = acc[nt] * rl;
            *(f32x4*)(ob + nt * 16 + lg * 4) = o;
        }
    } else {
        unsigned short* op = OP + (size_t)pslot * (QBLK * DIM) + (size_t)(w * 16 + l15) * DIM;
#pragma unroll
        for (int nt = 0; nt < 16; ++nt) {
            u16x4 ph;
            ph.x = f2bf(acc[nt][0]); ph.y = f2bf(acc[nt][1]);
            ph.z = f2bf(acc[nt][2]); ph.w = f2bf(acc[nt][3]);
            *(u16x4*)(op + nt * 16 + lg * 4) = ph;
        }
        if (lg == 0) {
            float* mlp = ML + (size_t)pslot * (2 * QBLK);
            mlp[(w * 16 + l15) * 2]     = mrun;
            mlp[(w * 16 + l15) * 2 + 1] = lrun;
        }
    }
}

// one block per (b, qt, 32-row group); merges the chunk partials
__global__ __launch_bounds__(256) void attn_combine(
        const unsigned short* __restrict__ OP, const float* __restrict__ ML,
        float* __restrict__ Og) {
    const int id = blockIdx.x;          // (b*32+qt)*4 + rg  (512 blocks)
    const int rg = id & 3;
    const int bq = id >> 2;
    const int b  = bq >> 5;
    const int qt = bq & 31;
    const int g  = qt >> 2;
    const int C  = g + 1;
    const int sb = b * PERB + 2 * g * (g + 1) + (qt & 3) * C;
    const int d  = threadIdx.x;

    float* outb = Og + ((size_t)(b * S_LEN + qt * QBLK)) * DIM;
    for (int row = rg * 32; row < rg * 32 + 32; ++row) {
        float M = -1e30f;
        for (int c = 0; c < C; ++c)
            M = fmaxf(M, ML[(size_t)(sb + c) * (2 * QBLK) + row * 2]);
        float L = 0.f, o = 0.f;
        for (int c = 0; c < C; ++c) {
            float mm = ML[(size_t)(sb + c) * (2 * QBLK) + row * 2];
            float ll = ML[(size_t)(sb + c) * (2 * QBLK) + row * 2 + 1];
            float s  = __expf(mm - M);
            L += ll * s;
            o += s * bf2f(OP[((size_t)(sb + c) * QBLK + row) * DIM + d]);
        }
        outb[(size_t)row * DIM + d] = (L > 0.f) ? (o / L) : 0.f;
    }
}

extern "C" void kernel_launch(void* const* d_in, const int* in_sizes, int n_in,
                              void* d_out, int out_size, void* d_ws, size_t ws_size,
                              hipStream_t stream) {
    const float* q = (const float*)d_in[0];
    const float* k = (const float*)d_in[1];
    const float* v = (const float*)d_in[2];
    float* o = (float*)d_out;

    const size_t imgShorts = (size_t)256 * TILE_SH;             // 8 MB per array
    const size_t IMG = 2 * imgShorts * sizeof(unsigned short);  // 16 MB
    unsigned short* KW = (unsigned short*)d_ws;
    unsigned short* VW = KW + imgShorts;

    const int nslots = 4 * PERB;   // 576
    const size_t need = IMG
        + (size_t)nslots * (QBLK * DIM) * 2       // bf16 OP: 37.75 MB
        + (size_t)nslots * (2 * QBLK) * 4;        // fp32 ML
    if (ws_size < IMG) return;

    hipLaunchKernelGGL(prepass, dim3(256), dim3(256), 0, stream, k, v, KW, VW);
    if (ws_size >= need) {
        unsigned short* OP = (unsigned short*)((char*)d_ws + IMG);
        float* ML = (float*)(OP + (size_t)nslots * (QBLK * DIM));
        hipLaunchKernelGGL((attn_part<false>), dim3(nslots), dim3(512), 0, stream,
                           q, KW, VW, OP, ML, o);
        hipLaunchKernelGGL(attn_combine, dim3(512), dim3(256), 0, stream,
                           OP, ML, o);
    } else {
        hipLaunchKernelGGL((attn_part<true>), dim3(128), dim3(512), 0, stream,
                           q, KW, VW, (unsigned short*)nullptr, (float*)nullptr, o);
    }
}

// Round 8
// 212.329 us; speedup vs baseline: 1.8942x; 1.8942x over previous
//
#include <hip/hip_runtime.h>

#define S_LEN 4096
#define DIM   256
#define QBLK  128
#define KVBLK 64
#define PERB  144            // chunk slots per batch (QBLK=128, CH=8 kv-tiles)
#define TILE_SH (KVBLK * DIM)   // shorts per 32KB tile image

typedef __attribute__((ext_vector_type(4))) float f32x4;
typedef __attribute__((ext_vector_type(8))) short bf16x8;
typedef __attribute__((ext_vector_type(4))) unsigned short u16x4;
typedef __attribute__((ext_vector_type(8))) unsigned short u16x8;

__device__ __forceinline__ unsigned short f2bf(float x) {
    union { float f; unsigned u; } v; v.f = x;
    unsigned r = v.u + 0x7FFFu + ((v.u >> 16) & 1u);
    return (unsigned short)(r >> 16);
}
__device__ __forceinline__ float bf2f(unsigned short h) {
    union { unsigned u; float f; } v; v.u = ((unsigned)h) << 16;
    return v.f;
}

// async global->LDS, 16B/lane; LDS dest = wave-uniform base + lane*16
__device__ __forceinline__ void g2l16(const unsigned short* g, unsigned short* s) {
    __builtin_amdgcn_global_load_lds(
        (const __attribute__((address_space(1))) unsigned int*)g,
        (__attribute__((address_space(3))) unsigned int*)s, 16, 0, 0);
}

// ---------- prepass: one block per (b,tile); coalesced image writes ----------
__global__ __launch_bounds__(256) void prepass(
        const float* __restrict__ K, const float* __restrict__ V,
        unsigned short* __restrict__ KW, unsigned short* __restrict__ VW) {
    __shared__ unsigned short vt[TILE_SH];
    const int tile = blockIdx.x;              // b*64 + t  (256 blocks)
    const int tid  = threadIdx.x;
    const float* ks = K + (size_t)tile * (KVBLK * DIM);
    const float* vs = V + (size_t)tile * (KVBLK * DIM);

    // K image: direct coalesced u16x8 writes (XOR swizzle permutes within rows)
    char* kw = (char*)(KW + (size_t)tile * TILE_SH);
#pragma unroll
    for (int j = 0; j < 8; ++j) {
        int u = j * 256 + tid;                // 16B-unit index
        int row = u >> 5, c8 = u & 31;
        f32x4 a  = *(const f32x4*)(ks + row * DIM + c8 * 8);
        f32x4 bb = *(const f32x4*)(ks + row * DIM + c8 * 8 + 4);
        u16x8 h;
        h[0] = f2bf(a[0]);  h[1] = f2bf(a[1]);  h[2] = f2bf(a[2]);  h[3] = f2bf(a[3]);
        h[4] = f2bf(bb[0]); h[5] = f2bf(bb[1]); h[6] = f2bf(bb[2]); h[7] = f2bf(bb[3]);
        unsigned off = (unsigned)(row * 512 + c8 * 16) ^ (unsigned)((row & 7) << 4);
        *(u16x8*)(kw + off) = h;
    }

    // V^T image: build in LDS (coalesced col reads), dump linearly
    {
        int col = tid;
#pragma unroll
        for (int r8 = 0; r8 < 8; ++r8) {
            u16x8 h;
#pragma unroll
            for (int e = 0; e < 8; ++e) h[e] = f2bf(vs[(r8 * 8 + e) * DIM + col]);
            unsigned off = (unsigned)(col * 128 + r8 * 16) ^ (unsigned)((col & 7) << 4);
            *(u16x8*)((char*)vt + off) = h;
        }
    }
    __syncthreads();
    char* vw = (char*)(VW + (size_t)tile * TILE_SH);
#pragma unroll
    for (int j = 0; j < 8; ++j) {
        int u = j * 256 + tid;
        *(u16x8*)(vw + u * 16) = *(const u16x8*)((const char*)vt + u * 16);
    }
}

// ---------- main flash kernel: 8 waves, QBLK=128 ----------
// NOTE: __launch_bounds__ 2nd arg = min BLOCKS/CU on this toolchain (measured:
// (512,4) capped VGPR at exactly 64, (512,2) at 128). (512,2) -> cap 128;
// natural demand ~112 (R6) -> no spill, 2 blocks/CU, 4 waves/SIMD.
template<bool DIRECT>
__global__ __launch_bounds__(512, 2) void attn_part(
        const float* __restrict__ Qg, const unsigned short* __restrict__ KW,
        const unsigned short* __restrict__ VW, unsigned short* __restrict__ OP,
        float* __restrict__ ML, float* __restrict__ Og) {
    __shared__ unsigned short Ksh[TILE_SH];       // [64][256] bf16, swz image
    __shared__ unsigned short VshT[TILE_SH];      // [256][64] bf16 (V^T), swz image
    __shared__ unsigned short Psh[8][16 * KVBLK]; // per-wave [q=16][k=64] bf16, swz

    const int tid = threadIdx.x;
    const int w   = tid >> 6;      // wave 0..7
    const int l   = tid & 63;
    const int l15 = l & 15;
    const int lg  = l >> 4;

    int b, qt, t0, t1, pslot;
    if (DIRECT) {
        b = blockIdx.x & 3; qt = blockIdx.x >> 2;
        t0 = 0; t1 = 2 * qt + 2; pslot = 0;
    } else {
        const int id = blockIdx.x;
        b = id / PERB;
        int s = (PERB - 1) - (id - b * PERB);   // heavy chunks first
        int g = 0;
        while (s >= 4 * (g + 1)) { s -= 4 * (g + 1); ++g; }
        qt = 4 * g + s / (g + 1);
        const int chunk = s - (s / (g + 1)) * (g + 1);
        t0 = chunk * 8;
        t1 = min(t0 + 8, 2 * qt + 2);
        pslot = b * PERB + 2 * g * (g + 1) + (qt - 4 * g) * (g + 1) + chunk;
    }
    const int qbase = qt * QBLK;
    const int wqlo  = qbase + w * 16;   // this wave's lowest q-row

    // ---------- Q fragments (16 rows/wave, scale 1/16 folded) ----------
    const int qrow = wqlo + l15;
    const float* qp = Qg + (size_t)(b * S_LEN + qrow) * DIM + lg * 8;
    bf16x8 qf[8];
#pragma unroll
    for (int ks = 0; ks < 8; ++ks) {
        f32x4 a = *(const f32x4*)(qp + ks * 32);
        f32x4 c = *(const f32x4*)(qp + ks * 32 + 4);
        bf16x8 f;
        f[0] = (short)f2bf(a[0] * 0.0625f); f[1] = (short)f2bf(a[1] * 0.0625f);
        f[2] = (short)f2bf(a[2] * 0.0625f); f[3] = (short)f2bf(a[3] * 0.0625f);
        f[4] = (short)f2bf(c[0] * 0.0625f); f[5] = (short)f2bf(c[1] * 0.0625f);
        f[6] = (short)f2bf(c[2] * 0.0625f); f[7] = (short)f2bf(c[3] * 0.0625f);
        qf[ks] = f;
    }

    f32x4 acc[16];
#pragma unroll
    for (int i = 0; i < 16; ++i) acc[i] = (f32x4)0.0f;
    float mrun = -1e30f, lrun = 0.f;

    for (int t = t0; t < t1; ++t) {
        // ------- stage tile images via async global->LDS (8 instrs/wave) -------
        {
            const unsigned short* kimg = KW + (size_t)(b * 64 + t) * TILE_SH + w * 2048 + l * 8;
            const unsigned short* vimg = VW + (size_t)(b * 64 + t) * TILE_SH + w * 2048 + l * 8;
            unsigned short* kd = &Ksh[w * 2048];
            unsigned short* vd = &VshT[w * 2048];
#pragma unroll
            for (int i = 0; i < 4; ++i) {
                g2l16(kimg + i * 512, kd + i * 512);
                g2l16(vimg + i * 512, vd + i * 512);
            }
        }
        __syncthreads();

        const bool skip = (t * KVBLK >= wqlo + 16);          // tile fully masked for wave
        const bool msk  = (t * KVBLK + KVBLK - 1 >= wqlo);   // diagonal region

        if (!skip) {
            // ---------------- S^T = K (Q*scale)^T ----------------
            f32x4 sacc[4];
#pragma unroll
            for (int j = 0; j < 4; ++j) sacc[j] = (f32x4)0.0f;
#pragma unroll
            for (int ks = 0; ks < 8; ++ks) {
#pragma unroll
                for (int jt = 0; jt < 4; ++jt) {
                    int j = jt * 16 + l15;
                    unsigned off = (unsigned)(j * 512 + (ks * 32 + lg * 8) * 2);
                    off ^= (unsigned)((j & 7) << 4);
                    bf16x8 kb = *(const bf16x8*)((const char*)Ksh + off);
                    sacc[jt] = __builtin_amdgcn_mfma_f32_16x16x32_bf16(kb, qf[ks], sacc[jt], 0, 0, 0);
                }
            }

            // ---------------- causal mask (strict j < i) ----------------
            if (msk) {
                const int qg = wqlo + l15;
#pragma unroll
                for (int jt = 0; jt < 4; ++jt)
#pragma unroll
                    for (int rr = 0; rr < 4; ++rr) {
                        int kg = t * KVBLK + jt * 16 + lg * 4 + rr;
                        if (kg >= qg) sacc[jt][rr] = -3e38f;
                    }
            }

            // ---------------- online softmax, in registers ----------------
            {
                float m0 = fmaxf(fmaxf(sacc[0][0], sacc[0][1]), fmaxf(sacc[0][2], sacc[0][3]));
                float m1 = fmaxf(fmaxf(sacc[1][0], sacc[1][1]), fmaxf(sacc[1][2], sacc[1][3]));
                float m2 = fmaxf(fmaxf(sacc[2][0], sacc[2][1]), fmaxf(sacc[2][2], sacc[2][3]));
                float m3 = fmaxf(fmaxf(sacc[3][0], sacc[3][1]), fmaxf(sacc[3][2], sacc[3][3]));
                float mx = fmaxf(fmaxf(m0, m1), fmaxf(m2, m3));
                mx = fmaxf(mx, __shfl_xor(mx, 16));
                mx = fmaxf(mx, __shfl_xor(mx, 32));
                float mnew = fmaxf(mrun, mx);
                float corr = __expf(mrun - mnew);
                mrun = mnew;
                float ls = 0.f;
#pragma unroll
                for (int jt = 0; jt < 4; ++jt)
#pragma unroll
                    for (int rr = 0; rr < 4; ++rr) {
                        float p = __expf(sacc[jt][rr] - mnew);
                        sacc[jt][rr] = p;
                        ls += p;
                    }
                ls += __shfl_xor(ls, 16);
                ls += __shfl_xor(ls, 32);
                lrun = lrun * corr + ls;
#pragma unroll
                for (int nt = 0; nt < 16; ++nt) acc[nt] *= corr;
            }

            // ---------------- P^T -> per-wave LDS (4x ds_write_b64) ----------------
            {
                char* pw = (char*)&Psh[w][0];
                unsigned base = (unsigned)(l15 * 128 + lg * 8) ^ (unsigned)((l15 & 7) << 4);
#pragma unroll
                for (int jt = 0; jt < 4; ++jt) {
                    u16x4 pk;
                    pk.x = f2bf(sacc[jt][0]); pk.y = f2bf(sacc[jt][1]);
                    pk.z = f2bf(sacc[jt][2]); pk.w = f2bf(sacc[jt][3]);
                    *(u16x4*)(pw + (base ^ (unsigned)(jt * 32))) = pk;
                }
            }

            // ---------------- O^T += V^T P^T ----------------
#pragma unroll
            for (int ks = 0; ks < 2; ++ks) {
                unsigned poff = (unsigned)(l15 * 128 + ks * 64 + lg * 16);
                poff ^= (unsigned)((l15 & 7) << 4);
                bf16x8 pb = *(const bf16x8*)((const char*)&Psh[w][0] + poff);
#pragma unroll
                for (int nt = 0; nt < 16; ++nt) {
                    unsigned voff = (unsigned)((nt * 16 + l15) * 128 + ks * 64 + lg * 16);
                    voff ^= (unsigned)((l15 & 7) << 4);
                    bf16x8 va = *(const bf16x8*)((const char*)VshT + voff);
                    acc[nt] = __builtin_amdgcn_mfma_f32_16x16x32_bf16(va, pb, acc[nt], 0, 0, 0);
                }
            }
        }
        __syncthreads();
    }

    if (DIRECT) {
        float rl = (lrun > 0.f) ? (1.0f / lrun) : 0.f;
        float* ob = Og + (size_t)(b * S_LEN + wqlo + l15) * DIM;
#pragma unroll
        for (int nt = 0; nt < 16; ++nt) {
            f32x4 o = acc[nt] * rl;
            *(f32x4*)(ob + nt * 16 + lg * 4) = o;
        }
    } else {
        unsigned short* op = OP + (size_t)pslot * (QBLK * DIM) + (size_t)(w * 16 + l15) * DIM;
#pragma unroll
        for (int nt = 0; nt < 16; ++nt) {
            u16x4 ph;
            ph.x = f2bf(acc[nt][0]); ph.y = f2bf(acc[nt][1]);
            ph.z = f2bf(acc[nt][2]); ph.w = f2bf(acc[nt][3]);
            *(u16x4*)(op + nt * 16 + lg * 4) = ph;
        }
        if (lg == 0) {
            float* mlp = ML + (size_t)pslot * (2 * QBLK);
            mlp[(w * 16 + l15) * 2]     = mrun;
            mlp[(w * 16 + l15) * 2 + 1] = lrun;
        }
    }
}

// one block per (b, qt, 32-row group); merges the chunk partials
__global__ __launch_bounds__(256) void attn_combine(
        const unsigned short* __restrict__ OP, const float* __restrict__ ML,
        float* __restrict__ Og) {
    const int id = blockIdx.x;          // (b*32+qt)*4 + rg  (512 blocks)
    const int rg = id & 3;
    const int bq = id >> 2;
    const int b  = bq >> 5;
    const int qt = bq & 31;
    const int g  = qt >> 2;
    const int C  = g + 1;
    const int sb = b * PERB + 2 * g * (g + 1) + (qt & 3) * C;
    const int d  = threadIdx.x;

    float* outb = Og + ((size_t)(b * S_LEN + qt * QBLK)) * DIM;
    for (int row = rg * 32; row < rg * 32 + 32; ++row) {
        float M = -1e30f;
        for (int c = 0; c < C; ++c)
            M = fmaxf(M, ML[(size_t)(sb + c) * (2 * QBLK) + row * 2]);
        float L = 0.f, o = 0.f;
        for (int c = 0; c < C; ++c) {
            float mm = ML[(size_t)(sb + c) * (2 * QBLK) + row * 2];
            float ll = ML[(size_t)(sb + c) * (2 * QBLK) + row * 2 + 1];
            float s  = __expf(mm - M);
            L += ll * s;
            o += s * bf2f(OP[((size_t)(sb + c) * QBLK + row) * DIM + d]);
        }
        outb[(size_t)row * DIM + d] = (L > 0.f) ? (o / L) : 0.f;
    }
}

extern "C" void kernel_launch(void* const* d_in, const int* in_sizes, int n_in,
                              void* d_out, int out_size, void* d_ws, size_t ws_size,
                              hipStream_t stream) {
    const float* q = (const float*)d_in[0];
    const float* k = (const float*)d_in[1];
    const float* v = (const float*)d_in[2];
    float* o = (float*)d_out;

    const size_t imgShorts = (size_t)256 * TILE_SH;             // 8 MB per array
    const size_t IMG = 2 * imgShorts * sizeof(unsigned short);  // 16 MB
    unsigned short* KW = (unsigned short*)d_ws;
    unsigned short* VW = KW + imgShorts;

    const int nslots = 4 * PERB;   // 576
    const size_t need = IMG
        + (size_t)nslots * (QBLK * DIM) * 2       // bf16 OP: 37.75 MB
        + (size_t)nslots * (2 * QBLK) * 4;        // fp32 ML
    if (ws_size < IMG) return;

    hipLaunchKernelGGL(prepass, dim3(256), dim3(256), 0, stream, k, v, KW, VW);
    if (ws_size >= need) {
        unsigned short* OP = (unsigned short*)((char*)d_ws + IMG);
        float* ML = (float*)(OP + (size_t)nslots * (QBLK * DIM));
        hipLaunchKernelGGL((attn_part<false>), dim3(nslots), dim3(512), 0, stream,
                           q, KW, VW, OP, ML, o);
        hipLaunchKernelGGL(attn_combine, dim3(512), dim3(256), 0, stream,
                           OP, ML, o);
    } else {
        hipLaunchKernelGGL((attn_part<true>), dim3(128), dim3(512), 0, stream,
                           q, KW, VW, (unsigned short*)nullptr, (float*)nullptr, o);
    }
}

// Round 9
// 126.978 us; speedup vs baseline: 3.1675x; 1.6722x over previous
//
#include <hip/hip_runtime.h>

#define S_LEN 4096
#define DIM   256
#define QBLK  128
#define KVBLK 64
#define CH    16             // kv-tiles per chunk
#define PERB  80             // chunk slots per batch: sum_g 8*(g+1), g=0..3
#define TILE_SH (KVBLK * DIM)   // shorts per 32KB tile image

typedef __attribute__((ext_vector_type(4))) float f32x4;
typedef __attribute__((ext_vector_type(8))) short bf16x8;
typedef __attribute__((ext_vector_type(4))) unsigned short u16x4;
typedef __attribute__((ext_vector_type(8))) unsigned short u16x8;

__device__ __forceinline__ unsigned short f2bf(float x) {
    union { float f; unsigned u; } v; v.f = x;
    unsigned r = v.u + 0x7FFFu + ((v.u >> 16) & 1u);
    return (unsigned short)(r >> 16);
}
__device__ __forceinline__ float bf2f(unsigned short h) {
    union { unsigned u; float f; } v; v.u = ((unsigned)h) << 16;
    return v.f;
}

// async global->LDS, 16B/lane; LDS dest = wave-uniform base + lane*16
__device__ __forceinline__ void g2l16(const unsigned short* g, unsigned short* s) {
    __builtin_amdgcn_global_load_lds(
        (const __attribute__((address_space(1))) unsigned int*)g,
        (__attribute__((address_space(3))) unsigned int*)s, 16, 0, 0);
}

// ---------- prepass: one block per (b,tile); coalesced image writes ----------
__global__ __launch_bounds__(256) void prepass(
        const float* __restrict__ K, const float* __restrict__ V,
        unsigned short* __restrict__ KW, unsigned short* __restrict__ VW) {
    __shared__ unsigned short vt[TILE_SH];
    const int tile = blockIdx.x;              // b*64 + t  (256 blocks)
    const int tid  = threadIdx.x;
    const float* ks = K + (size_t)tile * (KVBLK * DIM);
    const float* vs = V + (size_t)tile * (KVBLK * DIM);

    char* kw = (char*)(KW + (size_t)tile * TILE_SH);
#pragma unroll
    for (int j = 0; j < 8; ++j) {
        int u = j * 256 + tid;                // 16B-unit index
        int row = u >> 5, c8 = u & 31;
        f32x4 a  = *(const f32x4*)(ks + row * DIM + c8 * 8);
        f32x4 bb = *(const f32x4*)(ks + row * DIM + c8 * 8 + 4);
        u16x8 h;
        h[0] = f2bf(a[0]);  h[1] = f2bf(a[1]);  h[2] = f2bf(a[2]);  h[3] = f2bf(a[3]);
        h[4] = f2bf(bb[0]); h[5] = f2bf(bb[1]); h[6] = f2bf(bb[2]); h[7] = f2bf(bb[3]);
        unsigned off = (unsigned)(row * 512 + c8 * 16) ^ (unsigned)((row & 7) << 4);
        *(u16x8*)(kw + off) = h;
    }

    {
        int col = tid;
#pragma unroll
        for (int r8 = 0; r8 < 8; ++r8) {
            u16x8 h;
#pragma unroll
            for (int e = 0; e < 8; ++e) h[e] = f2bf(vs[(r8 * 8 + e) * DIM + col]);
            unsigned off = (unsigned)(col * 128 + r8 * 16) ^ (unsigned)((col & 7) << 4);
            *(u16x8*)((char*)vt + off) = h;
        }
    }
    __syncthreads();
    char* vw = (char*)(VW + (size_t)tile * TILE_SH);
#pragma unroll
    for (int j = 0; j < 8; ++j) {
        int u = j * 256 + tid;
        *(u16x8*)(vw + u * 16) = *(const u16x8*)((const char*)vt + u * 16);
    }
}

// ---------- main flash kernel: 8 waves, QBLK=128, double-buffered staging ----------
// NOTE: __launch_bounds__ 2nd arg behaves as min BLOCKS/CU here (measured R7/R8:
// (512,4)->64 VGPR cap, (512,2)->128). LDS 144KB -> 1 block/CU anyway; use (512,1).
template<bool DIRECT>
__global__ __launch_bounds__(512, 1) void attn_part(
        const float* __restrict__ Qg, const unsigned short* __restrict__ KW,
        const unsigned short* __restrict__ VW, unsigned short* __restrict__ OP,
        float* __restrict__ ML, float* __restrict__ Og) {
    __shared__ unsigned short Ksh[2][TILE_SH];    // dbuf [64][256] bf16 swz images
    __shared__ unsigned short VshT[2][TILE_SH];   // dbuf [256][64] bf16 (V^T) swz
    __shared__ unsigned short Psh[8][16 * KVBLK]; // per-wave [q=16][k=64] bf16, swz

    const int tid = threadIdx.x;
    const int w   = tid >> 6;      // wave 0..7
    const int l   = tid & 63;
    const int l15 = l & 15;
    const int lg  = l >> 4;

    int b, qt, t0, t1, pslot;
    if (DIRECT) {
        b = blockIdx.x & 3; qt = blockIdx.x >> 2;
        t0 = 0; t1 = 2 * qt + 2; pslot = 0;
    } else {
        const int id  = blockIdx.x;
        const int xcd = id & 7;              // XCD pinning: batch -> 2 XCDs
        b = xcd >> 1;
        int s = (PERB - 1) - ((id >> 3) * 2 + (xcd & 1));   // heavy chunks first
        int g = 0;
        while (s >= 8 * (g + 1)) { s -= 8 * (g + 1); ++g; }
        qt = 8 * g + s / (g + 1);
        const int chunk = s - (s / (g + 1)) * (g + 1);
        t0 = chunk * CH;
        t1 = min(t0 + CH, 2 * qt + 2);
        pslot = b * PERB + 4 * g * (g + 1) + (qt - 8 * g) * (g + 1) + chunk;
    }
    const int qbase = qt * QBLK;
    const int wqlo  = qbase + w * 16;
    const bool single = DIRECT || (t0 == 0 && t1 == 2 * qt + 2);

    // ---------- Q fragments (16 rows/wave, scale 1/16 folded) ----------
    const int qrow = wqlo + l15;
    const float* qp = Qg + (size_t)(b * S_LEN + qrow) * DIM + lg * 8;
    bf16x8 qf[8];
#pragma unroll
    for (int ks = 0; ks < 8; ++ks) {
        f32x4 a = *(const f32x4*)(qp + ks * 32);
        f32x4 c = *(const f32x4*)(qp + ks * 32 + 4);
        bf16x8 f;
        f[0] = (short)f2bf(a[0] * 0.0625f); f[1] = (short)f2bf(a[1] * 0.0625f);
        f[2] = (short)f2bf(a[2] * 0.0625f); f[3] = (short)f2bf(a[3] * 0.0625f);
        f[4] = (short)f2bf(c[0] * 0.0625f); f[5] = (short)f2bf(c[1] * 0.0625f);
        f[6] = (short)f2bf(c[2] * 0.0625f); f[7] = (short)f2bf(c[3] * 0.0625f);
        qf[ks] = f;
    }

    f32x4 acc[16];
#pragma unroll
    for (int i = 0; i < 16; ++i) acc[i] = (f32x4)0.0f;
    float mrun = -1e30f, lrun = 0.f;

    const size_t imgBase = (size_t)(b * 64) * TILE_SH + w * 2048 + l * 8;

    // -------- prologue: stage tile t0 -> buffer 0 --------
    {
        const unsigned short* kimg = KW + imgBase + (size_t)t0 * TILE_SH;
        const unsigned short* vimg = VW + imgBase + (size_t)t0 * TILE_SH;
        unsigned short* kd = &Ksh[0][w * 2048];
        unsigned short* vd = &VshT[0][w * 2048];
#pragma unroll
        for (int i = 0; i < 4; ++i) {
            g2l16(kimg + i * 512, kd + i * 512);
            g2l16(vimg + i * 512, vd + i * 512);
        }
    }
    __syncthreads();

    for (int t = t0; t < t1; ++t) {
        const int cur = (t - t0) & 1;

        // ------- issue next tile's loads into the other buffer (hidden under compute) -------
        if (t + 1 < t1) {
            const unsigned short* kimg = KW + imgBase + (size_t)(t + 1) * TILE_SH;
            const unsigned short* vimg = VW + imgBase + (size_t)(t + 1) * TILE_SH;
            unsigned short* kd = &Ksh[cur ^ 1][w * 2048];
            unsigned short* vd = &VshT[cur ^ 1][w * 2048];
#pragma unroll
            for (int i = 0; i < 4; ++i) {
                g2l16(kimg + i * 512, kd + i * 512);
                g2l16(vimg + i * 512, vd + i * 512);
            }
        }

        const bool skip = (t * KVBLK >= wqlo + 16);          // tile fully masked for wave
        const bool msk  = (t * KVBLK + KVBLK - 1 >= wqlo);   // diagonal region

        if (!skip) {
            // ---------------- S^T = K (Q*scale)^T ----------------
            f32x4 sacc[4];
#pragma unroll
            for (int j = 0; j < 4; ++j) sacc[j] = (f32x4)0.0f;
#pragma unroll
            for (int ks = 0; ks < 8; ++ks) {
#pragma unroll
                for (int jt = 0; jt < 4; ++jt) {
                    int j = jt * 16 + l15;
                    unsigned off = (unsigned)(j * 512 + (ks * 32 + lg * 8) * 2);
                    off ^= (unsigned)((j & 7) << 4);
                    bf16x8 kb = *(const bf16x8*)((const char*)Ksh[cur] + off);
                    sacc[jt] = __builtin_amdgcn_mfma_f32_16x16x32_bf16(kb, qf[ks], sacc[jt], 0, 0, 0);
                }
            }

            // ---------------- causal mask (strict j < i) ----------------
            if (msk) {
                const int qg = wqlo + l15;
#pragma unroll
                for (int jt = 0; jt < 4; ++jt)
#pragma unroll
                    for (int rr = 0; rr < 4; ++rr) {
                        int kg = t * KVBLK + jt * 16 + lg * 4 + rr;
                        if (kg >= qg) sacc[jt][rr] = -3e38f;
                    }
            }

            // ---------------- online softmax, in registers ----------------
            {
                float m0 = fmaxf(fmaxf(sacc[0][0], sacc[0][1]), fmaxf(sacc[0][2], sacc[0][3]));
                float m1 = fmaxf(fmaxf(sacc[1][0], sacc[1][1]), fmaxf(sacc[1][2], sacc[1][3]));
                float m2 = fmaxf(fmaxf(sacc[2][0], sacc[2][1]), fmaxf(sacc[2][2], sacc[2][3]));
                float m3 = fmaxf(fmaxf(sacc[3][0], sacc[3][1]), fmaxf(sacc[3][2], sacc[3][3]));
                float mx = fmaxf(fmaxf(m0, m1), fmaxf(m2, m3));
                mx = fmaxf(mx, __shfl_xor(mx, 16));
                mx = fmaxf(mx, __shfl_xor(mx, 32));
                float mnew = fmaxf(mrun, mx);
                float corr = __expf(mrun - mnew);
                mrun = mnew;
                float ls = 0.f;
#pragma unroll
                for (int jt = 0; jt < 4; ++jt)
#pragma unroll
                    for (int rr = 0; rr < 4; ++rr) {
                        float p = __expf(sacc[jt][rr] - mnew);
                        sacc[jt][rr] = p;
                        ls += p;
                    }
                ls += __shfl_xor(ls, 16);
                ls += __shfl_xor(ls, 32);
                lrun = lrun * corr + ls;
#pragma unroll
                for (int nt = 0; nt < 16; ++nt) acc[nt] *= corr;
            }

            // ---------------- P^T -> per-wave LDS (4x ds_write_b64) ----------------
            {
                char* pw = (char*)&Psh[w][0];
                unsigned base = (unsigned)(l15 * 128 + lg * 8) ^ (unsigned)((l15 & 7) << 4);
#pragma unroll
                for (int jt = 0; jt < 4; ++jt) {
                    u16x4 pk;
                    pk.x = f2bf(sacc[jt][0]); pk.y = f2bf(sacc[jt][1]);
                    pk.z = f2bf(sacc[jt][2]); pk.w = f2bf(sacc[jt][3]);
                    *(u16x4*)(pw + (base ^ (unsigned)(jt * 32))) = pk;
                }
            }

            // ---------------- O^T += V^T P^T ----------------
#pragma unroll
            for (int ks = 0; ks < 2; ++ks) {
                unsigned poff = (unsigned)(l15 * 128 + ks * 64 + lg * 16);
                poff ^= (unsigned)((l15 & 7) << 4);
                bf16x8 pb = *(const bf16x8*)((const char*)&Psh[w][0] + poff);
#pragma unroll
                for (int nt = 0; nt < 16; ++nt) {
                    unsigned voff = (unsigned)((nt * 16 + l15) * 128 + ks * 64 + lg * 16);
                    voff ^= (unsigned)((l15 & 7) << 4);
                    bf16x8 va = *(const bf16x8*)((const char*)VshT[cur] + voff);
                    acc[nt] = __builtin_amdgcn_mfma_f32_16x16x32_bf16(va, pb, acc[nt], 0, 0, 0);
                }
            }
        }
        __syncthreads();   // drains next-tile loads; syncs buffer reuse
    }

    if (single) {
        float rl = (lrun > 0.f) ? (1.0f / lrun) : 0.f;
        float* ob = Og + (size_t)(b * S_LEN + wqlo + l15) * DIM;
#pragma unroll
        for (int nt = 0; nt < 16; ++nt) {
            f32x4 o = acc[nt] * rl;
            *(f32x4*)(ob + nt * 16 + lg * 4) = o;
        }
    } else {
        unsigned short* op = OP + (size_t)pslot * (QBLK * DIM) + (size_t)(w * 16 + l15) * DIM;
#pragma unroll
        for (int nt = 0; nt < 16; ++nt) {
            u16x4 ph;
            ph.x = f2bf(acc[nt][0]); ph.y = f2bf(acc[nt][1]);
            ph.z = f2bf(acc[nt][2]); ph.w = f2bf(acc[nt][3]);
            *(u16x4*)(op + nt * 16 + lg * 4) = ph;
        }
        if (lg == 0) {
            float* mlp = ML + (size_t)pslot * (2 * QBLK);
            mlp[(w * 16 + l15) * 2]     = mrun;
            mlp[(w * 16 + l15) * 2 + 1] = lrun;
        }
    }
}

// blocks for (b, qt>=8, 32-row group); merges C chunk partials, vectorized
__global__ __launch_bounds__(256) void attn_combine(
        const unsigned short* __restrict__ OP, const float* __restrict__ ML,
        float* __restrict__ Og) {
    const int id = blockIdx.x;          // (b*24 + (qt-8))*4 + rg ; 384 blocks
    const int rg = id & 3;
    const int bq = id >> 2;
    const int b  = bq / 24;
    const int qt = 8 + bq % 24;
    const int g  = qt >> 3;
    const int C  = g + 1;
    const size_t sb = (size_t)b * PERB + 4 * g * (g + 1) + (qt - 8 * g) * C;
    const int tid = threadIdx.x;

    float* outb = Og + ((size_t)(b * S_LEN + qt * QBLK)) * DIM;
#pragma unroll
    for (int j = 0; j < 4; ++j) {
        int u   = j * 256 + tid;            // 32 rows x 32 d8-units
        int row = rg * 32 + (u >> 5);
        int d8  = u & 31;
        float M = -1e30f;
        for (int c = 0; c < C; ++c)
            M = fmaxf(M, ML[(sb + c) * (2 * QBLK) + row * 2]);
        float L = 0.f;
        float o[8];
#pragma unroll
        for (int e = 0; e < 8; ++e) o[e] = 0.f;
        for (int c = 0; c < C; ++c) {
            float mm = ML[(sb + c) * (2 * QBLK) + row * 2];
            float ll = ML[(sb + c) * (2 * QBLK) + row * 2 + 1];
            float s  = __expf(mm - M);
            L += ll * s;
            u16x8 ph = *(const u16x8*)(OP + ((sb + c) * QBLK + row) * DIM + d8 * 8);
#pragma unroll
            for (int e = 0; e < 8; ++e) o[e] += s * bf2f(ph[e]);
        }
        float rl = (L > 0.f) ? (1.0f / L) : 0.f;
        f32x4 o0, o1;
        o0[0] = o[0] * rl; o0[1] = o[1] * rl; o0[2] = o[2] * rl; o0[3] = o[3] * rl;
        o1[0] = o[4] * rl; o1[1] = o[5] * rl; o1[2] = o[6] * rl; o1[3] = o[7] * rl;
        *(f32x4*)(outb + (size_t)row * DIM + d8 * 8)     = o0;
        *(f32x4*)(outb + (size_t)row * DIM + d8 * 8 + 4) = o1;
    }
}

extern "C" void kernel_launch(void* const* d_in, const int* in_sizes, int n_in,
                              void* d_out, int out_size, void* d_ws, size_t ws_size,
                              hipStream_t stream) {
    const float* q = (const float*)d_in[0];
    const float* k = (const float*)d_in[1];
    const float* v = (const float*)d_in[2];
    float* o = (float*)d_out;

    const size_t imgShorts = (size_t)256 * TILE_SH;             // 8 MB per array
    const size_t IMG = 2 * imgShorts * sizeof(unsigned short);  // 16 MB
    unsigned short* KW = (unsigned short*)d_ws;
    unsigned short* VW = KW + imgShorts;

    const int nslots = 4 * PERB;   // 320
    const size_t need = IMG
        + (size_t)nslots * (QBLK * DIM) * 2       // bf16 OP: ~21 MB
        + (size_t)nslots * (2 * QBLK) * 4;        // fp32 ML
    if (ws_size < IMG) return;

    hipLaunchKernelGGL(prepass, dim3(256), dim3(256), 0, stream, k, v, KW, VW);
    if (ws_size >= need) {
        unsigned short* OP = (unsigned short*)((char*)d_ws + IMG);
        float* ML = (float*)(OP + (size_t)nslots * (QBLK * DIM));
        hipLaunchKernelGGL((attn_part<false>), dim3(nslots), dim3(512), 0, stream,
                           q, KW, VW, OP, ML, o);
        hipLaunchKernelGGL(attn_combine, dim3(384), dim3(256), 0, stream,
                           OP, ML, o);
    } else {
        hipLaunchKernelGGL((attn_part<true>), dim3(128), dim3(512), 0, stream,
                           q, KW, VW, (unsigned short*)nullptr, (float*)nullptr, o);
    }
}

// Round 10
// 107.960 us; speedup vs baseline: 3.7255x; 1.1762x over previous
//
#include <hip/hip_runtime.h>

#define S_LEN 4096
#define DIM   256
#define QBLK  128
#define KVBLK 64
#define TILE_SH (KVBLK * DIM)   // shorts per 32KB tile image
#define PER_B  1056             // items per batch: sum_qt (2qt+2), qt<32
#define NBLK   256

typedef __attribute__((ext_vector_type(4))) float f32x4;
typedef __attribute__((ext_vector_type(8))) short bf16x8;
typedef __attribute__((ext_vector_type(4))) unsigned short u16x4;
typedef __attribute__((ext_vector_type(8))) unsigned short u16x8;

__device__ __forceinline__ unsigned short f2bf(float x) {
    union { float f; unsigned u; } v; v.f = x;
    unsigned r = v.u + 0x7FFFu + ((v.u >> 16) & 1u);
    return (unsigned short)(r >> 16);
}
__device__ __forceinline__ float bf2f(unsigned short h) {
    union { unsigned u; float f; } v; v.u = ((unsigned)h) << 16;
    return v.f;
}

// async global->LDS, 16B/lane; LDS dest = wave-uniform base + lane*16
__device__ __forceinline__ void g2l16(const unsigned short* g, unsigned short* s) {
    __builtin_amdgcn_global_load_lds(
        (const __attribute__((address_space(1))) unsigned int*)g,
        (__attribute__((address_space(3))) unsigned int*)s, 16, 0, 0);
}

// flat item x -> (batch, q-tile, kv-tile);  x = b*1056 + qt*(qt+1) + t
__device__ __forceinline__ void decode_item(int x, int& b, int& qt, int& t) {
    b = x / PER_B;
    int r = x - b * PER_B;
    int q = (int)((__fsqrt_rn(4.0f * (float)r + 1.0f) - 1.0f) * 0.5f);
    while ((q + 1) * (q + 2) <= r) ++q;
    while (q * (q + 1) > r) --q;
    qt = q;
    t = r - q * (q + 1);
}

// ---------- prepass: one block per (b,tile); coalesced image writes ----------
__global__ __launch_bounds__(256) void prepass(
        const float* __restrict__ K, const float* __restrict__ V,
        unsigned short* __restrict__ KW, unsigned short* __restrict__ VW) {
    __shared__ unsigned short vt[TILE_SH];
    const int tile = blockIdx.x;              // b*64 + t  (256 blocks)
    const int tid  = threadIdx.x;
    const float* ks = K + (size_t)tile * (KVBLK * DIM);
    const float* vs = V + (size_t)tile * (KVBLK * DIM);

    char* kw = (char*)(KW + (size_t)tile * TILE_SH);
#pragma unroll
    for (int j = 0; j < 8; ++j) {
        int u = j * 256 + tid;                // 16B-unit index
        int row = u >> 5, c8 = u & 31;
        f32x4 a  = *(const f32x4*)(ks + row * DIM + c8 * 8);
        f32x4 bb = *(const f32x4*)(ks + row * DIM + c8 * 8 + 4);
        u16x8 h;
        h[0] = f2bf(a[0]);  h[1] = f2bf(a[1]);  h[2] = f2bf(a[2]);  h[3] = f2bf(a[3]);
        h[4] = f2bf(bb[0]); h[5] = f2bf(bb[1]); h[6] = f2bf(bb[2]); h[7] = f2bf(bb[3]);
        unsigned off = (unsigned)(row * 512 + c8 * 16) ^ (unsigned)((row & 7) << 4);
        *(u16x8*)(kw + off) = h;
    }
    {
        int col = tid;
#pragma unroll
        for (int r8 = 0; r8 < 8; ++r8) {
            u16x8 h;
#pragma unroll
            for (int e = 0; e < 8; ++e) h[e] = f2bf(vs[(r8 * 8 + e) * DIM + col]);
            unsigned off = (unsigned)(col * 128 + r8 * 16) ^ (unsigned)((col & 7) << 4);
            *(u16x8*)((char*)vt + off) = h;
        }
    }
    __syncthreads();
    char* vw = (char*)(VW + (size_t)tile * TILE_SH);
#pragma unroll
    for (int j = 0; j < 8; ++j) {
        int u = j * 256 + tid;
        *(u16x8*)(vw + u * 16) = *(const u16x8*)((const char*)vt + u * 16);
    }
}

// ---------- main flash kernel: flat work-list, perfectly packed ----------
// __launch_bounds__ 2nd arg = min BLOCKS/CU on this toolchain (R7/R8 measured).
template<bool PACKED>
__global__ __launch_bounds__(512, 1) void attn_flash(
        const float* __restrict__ Qg, const unsigned short* __restrict__ KW,
        const unsigned short* __restrict__ VW, unsigned short* __restrict__ OP,
        float* __restrict__ ML, float* __restrict__ Og) {
    __shared__ unsigned short Ksh[2][TILE_SH];    // dbuf K images
    __shared__ unsigned short VshT[2][TILE_SH];   // dbuf V^T images
    __shared__ unsigned short Psh[8][16 * KVBLK]; // per-wave P, swz

    const int tid = threadIdx.x;
    const int w   = tid >> 6;
    const int l   = tid & 63;
    const int l15 = l & 15;
    const int lg  = l >> 4;

    int s, e;
    if (PACKED) {
        const int i = blockIdx.x;
        s = (33 * i) >> 1;            // i * 16.5
        e = (33 * (i + 1)) >> 1;
    } else {
        const int b0 = blockIdx.x & 3, q0 = blockIdx.x >> 2;
        s = b0 * PER_B + q0 * (q0 + 1);
        e = s + 2 * q0 + 2;
    }

    int b, qt, t;
    decode_item(s, b, qt, t);
    int tstart = t;
    bool firstSec = true;

    bf16x8 qf[8];
    // ---- Q fragment loader (16 rows/wave, scale 1/16 folded) ----
    {
        const float* qp = Qg + (size_t)(b * S_LEN + qt * QBLK + w * 16 + l15) * DIM + lg * 8;
#pragma unroll
        for (int ks = 0; ks < 8; ++ks) {
            f32x4 a = *(const f32x4*)(qp + ks * 32);
            f32x4 c = *(const f32x4*)(qp + ks * 32 + 4);
            bf16x8 f;
            f[0] = (short)f2bf(a[0] * 0.0625f); f[1] = (short)f2bf(a[1] * 0.0625f);
            f[2] = (short)f2bf(a[2] * 0.0625f); f[3] = (short)f2bf(a[3] * 0.0625f);
            f[4] = (short)f2bf(c[0] * 0.0625f); f[5] = (short)f2bf(c[1] * 0.0625f);
            f[6] = (short)f2bf(c[2] * 0.0625f); f[7] = (short)f2bf(c[3] * 0.0625f);
            qf[ks] = f;
        }
    }

    f32x4 acc[16];
#pragma unroll
    for (int i = 0; i < 16; ++i) acc[i] = (f32x4)0.0f;
    float mrun = -1e30f, lrun = 0.f;

    // ---- prologue: stage item s into buffer 0 ----
    {
        const unsigned short* kimg = KW + (size_t)(b * 64 + t) * TILE_SH + w * 2048 + l * 8;
        const unsigned short* vimg = VW + (size_t)(b * 64 + t) * TILE_SH + w * 2048 + l * 8;
        unsigned short* kd = &Ksh[0][w * 2048];
        unsigned short* vd = &VshT[0][w * 2048];
#pragma unroll
        for (int i = 0; i < 4; ++i) {
            g2l16(kimg + i * 512, kd + i * 512);
            g2l16(vimg + i * 512, vd + i * 512);
        }
    }
    __syncthreads();

    int x = s, cur = 0;
    while (true) {
        const bool have_next = (x + 1 < e);
        int nb = b, nqt = qt, ntt = t + 1;
        const bool secEnd = !have_next || (ntt >= 2 * qt + 2);
        if (have_next) {
            if (ntt >= 2 * qt + 2) decode_item(x + 1, nb, nqt, ntt);
            const unsigned short* kimg = KW + (size_t)(nb * 64 + ntt) * TILE_SH + w * 2048 + l * 8;
            const unsigned short* vimg = VW + (size_t)(nb * 64 + ntt) * TILE_SH + w * 2048 + l * 8;
            unsigned short* kd = &Ksh[cur ^ 1][w * 2048];
            unsigned short* vd = &VshT[cur ^ 1][w * 2048];
#pragma unroll
            for (int i = 0; i < 4; ++i) {
                g2l16(kimg + i * 512, kd + i * 512);
                g2l16(vimg + i * 512, vd + i * 512);
            }
        }

        const int wqlo = qt * QBLK + w * 16;
        const bool skip = (t * KVBLK >= wqlo + 16);
        const bool msk  = (t * KVBLK + KVBLK - 1 >= wqlo);

        if (!skip) {
            // ---------------- S^T = K (Q*scale)^T ----------------
            f32x4 sacc[4];
#pragma unroll
            for (int j = 0; j < 4; ++j) sacc[j] = (f32x4)0.0f;
#pragma unroll
            for (int ks = 0; ks < 8; ++ks) {
#pragma unroll
                for (int jt = 0; jt < 4; ++jt) {
                    int j = jt * 16 + l15;
                    unsigned off = (unsigned)(j * 512 + (ks * 32 + lg * 8) * 2);
                    off ^= (unsigned)((j & 7) << 4);
                    bf16x8 kb = *(const bf16x8*)((const char*)Ksh[cur] + off);
                    sacc[jt] = __builtin_amdgcn_mfma_f32_16x16x32_bf16(kb, qf[ks], sacc[jt], 0, 0, 0);
                }
            }
            // ---------------- causal mask (strict j < i) ----------------
            if (msk) {
                const int qg = wqlo + l15;
#pragma unroll
                for (int jt = 0; jt < 4; ++jt)
#pragma unroll
                    for (int rr = 0; rr < 4; ++rr) {
                        int kg = t * KVBLK + jt * 16 + lg * 4 + rr;
                        if (kg >= qg) sacc[jt][rr] = -3e38f;
                    }
            }
            // ---------------- online softmax, in registers ----------------
            {
                float m0 = fmaxf(fmaxf(sacc[0][0], sacc[0][1]), fmaxf(sacc[0][2], sacc[0][3]));
                float m1 = fmaxf(fmaxf(sacc[1][0], sacc[1][1]), fmaxf(sacc[1][2], sacc[1][3]));
                float m2 = fmaxf(fmaxf(sacc[2][0], sacc[2][1]), fmaxf(sacc[2][2], sacc[2][3]));
                float m3 = fmaxf(fmaxf(sacc[3][0], sacc[3][1]), fmaxf(sacc[3][2], sacc[3][3]));
                float mx = fmaxf(fmaxf(m0, m1), fmaxf(m2, m3));
                mx = fmaxf(mx, __shfl_xor(mx, 16));
                mx = fmaxf(mx, __shfl_xor(mx, 32));
                float mnew = fmaxf(mrun, mx);
                float corr = __expf(mrun - mnew);
                mrun = mnew;
                float ls = 0.f;
#pragma unroll
                for (int jt = 0; jt < 4; ++jt)
#pragma unroll
                    for (int rr = 0; rr < 4; ++rr) {
                        float p = __expf(sacc[jt][rr] - mnew);
                        sacc[jt][rr] = p;
                        ls += p;
                    }
                ls += __shfl_xor(ls, 16);
                ls += __shfl_xor(ls, 32);
                lrun = lrun * corr + ls;
#pragma unroll
                for (int nt = 0; nt < 16; ++nt) acc[nt] *= corr;
            }
            // ---------------- P^T -> per-wave LDS ----------------
            {
                char* pw = (char*)&Psh[w][0];
                unsigned base = (unsigned)(l15 * 128 + lg * 8) ^ (unsigned)((l15 & 7) << 4);
#pragma unroll
                for (int jt = 0; jt < 4; ++jt) {
                    u16x4 pk;
                    pk.x = f2bf(sacc[jt][0]); pk.y = f2bf(sacc[jt][1]);
                    pk.z = f2bf(sacc[jt][2]); pk.w = f2bf(sacc[jt][3]);
                    *(u16x4*)(pw + (base ^ (unsigned)(jt * 32))) = pk;
                }
            }
            // ---------------- O^T += V^T P^T ----------------
#pragma unroll
            for (int ks = 0; ks < 2; ++ks) {
                unsigned poff = (unsigned)(l15 * 128 + ks * 64 + lg * 16);
                poff ^= (unsigned)((l15 & 7) << 4);
                bf16x8 pb = *(const bf16x8*)((const char*)&Psh[w][0] + poff);
#pragma unroll
                for (int nt = 0; nt < 16; ++nt) {
                    unsigned voff = (unsigned)((nt * 16 + l15) * 128 + ks * 64 + lg * 16);
                    voff ^= (unsigned)((l15 & 7) << 4);
                    bf16x8 va = *(const bf16x8*)((const char*)VshT[cur] + voff);
                    acc[nt] = __builtin_amdgcn_mfma_f32_16x16x32_bf16(va, pb, acc[nt], 0, 0, 0);
                }
            }
        }
        __syncthreads();   // drains next-tile loads; protects buffer reuse

        if (secEnd) {
            // -------- flush section for (b, qt) --------
            const bool complete = (tstart == 0) && (t == 2 * qt + 1);
            if (complete) {
                float rl = (lrun > 0.f) ? (1.0f / lrun) : 0.f;
                float* ob = Og + (size_t)(b * S_LEN + wqlo + l15) * DIM;
#pragma unroll
                for (int nt = 0; nt < 16; ++nt) {
                    f32x4 o = acc[nt] * rl;
                    *(f32x4*)(ob + nt * 16 + lg * 4) = o;
                }
            } else {
                const int slot = 2 * blockIdx.x + (firstSec ? 0 : 1);
                unsigned short* op = OP + (size_t)slot * (QBLK * DIM)
                                        + (size_t)(w * 16 + l15) * DIM;
#pragma unroll
                for (int nt = 0; nt < 16; ++nt) {
                    u16x4 ph;
                    ph.x = f2bf(acc[nt][0]); ph.y = f2bf(acc[nt][1]);
                    ph.z = f2bf(acc[nt][2]); ph.w = f2bf(acc[nt][3]);
                    *(u16x4*)(op + nt * 16 + lg * 4) = ph;
                }
                if (lg == 0) {
                    float* mlp = ML + (size_t)slot * (2 * QBLK);
                    mlp[(w * 16 + l15) * 2]     = mrun;
                    mlp[(w * 16 + l15) * 2 + 1] = lrun;
                }
            }
            if (!have_next) break;
            // -------- reinit for next section (nb, nqt) --------
            {
                const float* qp = Qg + (size_t)(nb * S_LEN + nqt * QBLK + w * 16 + l15) * DIM + lg * 8;
#pragma unroll
                for (int ks = 0; ks < 8; ++ks) {
                    f32x4 a = *(const f32x4*)(qp + ks * 32);
                    f32x4 c = *(const f32x4*)(qp + ks * 32 + 4);
                    bf16x8 f;
                    f[0] = (short)f2bf(a[0] * 0.0625f); f[1] = (short)f2bf(a[1] * 0.0625f);
                    f[2] = (short)f2bf(a[2] * 0.0625f); f[3] = (short)f2bf(a[3] * 0.0625f);
                    f[4] = (short)f2bf(c[0] * 0.0625f); f[5] = (short)f2bf(c[1] * 0.0625f);
                    f[6] = (short)f2bf(c[2] * 0.0625f); f[7] = (short)f2bf(c[3] * 0.0625f);
                    qf[ks] = f;
                }
            }
#pragma unroll
            for (int i = 0; i < 16; ++i) acc[i] = (f32x4)0.0f;
            mrun = -1e30f; lrun = 0.f;
            firstSec = false; tstart = 0;
        }
        ++x; b = nb; qt = nqt; t = ntt; cur ^= 1;
    }
}

// merges partial sections for (b, qt) spanning >1 block; 512 blocks
__global__ __launch_bounds__(256) void attn_combine(
        const unsigned short* __restrict__ OP, const float* __restrict__ ML,
        float* __restrict__ Og) {
    const int id = blockIdx.x;          // (b*32+qt)*4 + rg
    const int rg = id & 3;
    const int bq = id >> 2;
    const int b  = bq >> 5;
    const int qt = bq & 31;
    const int A  = b * PER_B + qt * (qt + 1);
    const int E  = A + 2 * qt + 2;
    const int j0 = (2 * A + 1) / 33;
    const int j1 = (2 * E - 1) / 33;
    if (j0 >= j1) return;               // handled direct in attn_flash
    const int C = j1 - j0 + 1;          // <= 5

    int slots[6];
    for (int c = 0; c < C; ++c) {
        int j  = j0 + c;
        int sj = (33 * j) >> 1;
        slots[c] = 2 * j + ((sj >= A) ? 0 : 1);
    }

    const int tid = threadIdx.x;
    float* outb = Og + ((size_t)(b * S_LEN + qt * QBLK)) * DIM;
#pragma unroll
    for (int jj = 0; jj < 4; ++jj) {
        int u   = jj * 256 + tid;           // 32 rows x 32 d8-units
        int row = rg * 32 + (u >> 5);
        int d8  = u & 31;
        float M = -1e30f;
        for (int c = 0; c < C; ++c)
            M = fmaxf(M, ML[(size_t)slots[c] * (2 * QBLK) + row * 2]);
        float L = 0.f;
        float o[8];
#pragma unroll
        for (int e2 = 0; e2 < 8; ++e2) o[e2] = 0.f;
        for (int c = 0; c < C; ++c) {
            float mm = ML[(size_t)slots[c] * (2 * QBLK) + row * 2];
            float ll = ML[(size_t)slots[c] * (2 * QBLK) + row * 2 + 1];
            float sc = __expf(mm - M);
            L += ll * sc;
            u16x8 ph = *(const u16x8*)(OP + ((size_t)slots[c] * QBLK + row) * DIM + d8 * 8);
#pragma unroll
            for (int e2 = 0; e2 < 8; ++e2) o[e2] += sc * bf2f(ph[e2]);
        }
        float rl = (L > 0.f) ? (1.0f / L) : 0.f;
        f32x4 o0, o1;
        o0[0] = o[0] * rl; o0[1] = o[1] * rl; o0[2] = o[2] * rl; o0[3] = o[3] * rl;
        o1[0] = o[4] * rl; o1[1] = o[5] * rl; o1[2] = o[6] * rl; o1[3] = o[7] * rl;
        *(f32x4*)(outb + (size_t)row * DIM + d8 * 8)     = o0;
        *(f32x4*)(outb + (size_t)row * DIM + d8 * 8 + 4) = o1;
    }
}

extern "C" void kernel_launch(void* const* d_in, const int* in_sizes, int n_in,
                              void* d_out, int out_size, void* d_ws, size_t ws_size,
                              hipStream_t stream) {
    const float* q = (const float*)d_in[0];
    const float* k = (const float*)d_in[1];
    const float* v = (const float*)d_in[2];
    float* o = (float*)d_out;

    const size_t imgShorts = (size_t)256 * TILE_SH;             // 8 MB per array
    const size_t IMG = 2 * imgShorts * sizeof(unsigned short);  // 16 MB
    unsigned short* KW = (unsigned short*)d_ws;
    unsigned short* VW = KW + imgShorts;

    const int nslots = 2 * NBLK;   // 512
    const size_t need = IMG
        + (size_t)nslots * (QBLK * DIM) * 2       // bf16 OP: 33.5 MB
        + (size_t)nslots * (2 * QBLK) * 4;        // fp32 ML
    if (ws_size < IMG) return;

    hipLaunchKernelGGL(prepass, dim3(256), dim3(256), 0, stream, k, v, KW, VW);
    if (ws_size >= need) {
        unsigned short* OP = (unsigned short*)((char*)d_ws + IMG);
        float* ML = (float*)(OP + (size_t)nslots * (QBLK * DIM));
        hipLaunchKernelGGL((attn_flash<true>), dim3(NBLK), dim3(512), 0, stream,
                           q, KW, VW, OP, ML, o);
        hipLaunchKernelGGL(attn_combine, dim3(512), dim3(256), 0, stream,
                           OP, ML, o);
    } else {
        hipLaunchKernelGGL((attn_flash<false>), dim3(128), dim3(512), 0, stream,
                           q, KW, VW, (unsigned short*)nullptr, (float*)nullptr, o);
    }
}